// Round 3
// baseline (85.913 us; speedup 1.0000x reference)
//
#include <hip/hip_runtime.h>
#include <hip/hip_bf16.h>

// Single-dispatch fused kernel:
//   64 blocks x 320 threads. Block n encodes image n (n<32: video pos n,
//   else patch n-32): Conv2d(4->64,3x3,pad=1)+ReLU+avgpool -> emb row.
//   Handoff: block writes flags[n]=MAGIC (device-scope release); wave 0
//   acquire-loads all 64 flags; any block seeing all 64 runs the match
//   phase (scores -> stable argsort -> greedy). Ties run match redundantly
//   and write identical outputs (benign). Poison-agnostic: flags start as
//   harness poison 0xAAAAAAAA (or 0), never MAGIC. No memset dispatch.

#define MAGIC 0x1F2E3D4C

__global__ __launch_bounds__(320) void fused_kernel(
    const float* __restrict__ v_latent,   // [4,4,10,8,8]
    const float* __restrict__ p_tensor,   // [32,4,10,8]
    const float* __restrict__ v_w,        // [64,4,3,3]
    const float* __restrict__ v_b,        // [64]
    const float* __restrict__ p_w,        // [64,4,3,3]
    const float* __restrict__ p_b,        // [64]
    float* emb,                           // ws: [64][64]
    int*   flags,                         // ws: [64]
    int* __restrict__ out)                // [32] int32
{
    __shared__ float xpad[4 * 12 * 12];   // padded tile, row len 12 (16B-align rows)
    __shared__ float partial[5 * 64];
    __shared__ int   do_match;
    __shared__ float ve[32 * 65];         // +1 pad: conflict-free column walks
    __shared__ float pe[32 * 65];
    __shared__ float sc[32 * 33];
    __shared__ int   pref2[32 * 33];      // pad 33: greedy column read conflict-free
    __shared__ int   claim[32];
    __shared__ int   taken[32];

    const int n   = blockIdx.x;
    const int tid = threadIdx.x;
    const bool is_video = (n < 32);
    const float* w    = is_video ? v_w : p_w;
    const float* bias = is_video ? v_b : p_b;

    // ---- stage input: zero pad ring, then interior (exactly 320 elems) ----
    for (int s = tid; s < 576; s += 320) xpad[s] = 0.f;
    __syncthreads();
    {
        const int ic  = tid / 80;
        const int rem = tid % 80;
        const int h   = rem >> 3;
        const int ww  = rem & 7;
        float val;
        if (is_video) {
            const int b = n >> 3, d = n & 7;
            val = v_latent[ic * 2560 + b * 640 + h * 64 + d * 8 + ww];
        } else {
            val = p_tensor[(n - 32) * 320 + ic * 80 + h * 8 + ww];
        }
        xpad[(ic * 12 + h + 1) * 12 + (ww + 1)] = val;
    }

    const int oc  = tid & 63;
    const int seg = tid >> 6;          // 0..4
    const int h0  = seg * 2;           // output rows h0, h0+1

    // 36 conv weights for this oc (144 B aligned -> 9 float4), global loads
    // overlap the LDS staging barrier below.
    float wr[36];
    {
        const float4* w4 = (const float4*)(w + oc * 36);
#pragma unroll
        for (int i = 0; i < 9; ++i) {
            const float4 q = w4[i];
            wr[i * 4 + 0] = q.x; wr[i * 4 + 1] = q.y;
            wr[i * 4 + 2] = q.z; wr[i * 4 + 3] = q.w;
        }
    }
    const float bval = bias[oc];
    __syncthreads();

    // ---- conv: per ic, pull 4 padded rows via ds_read_b128 (wave-uniform
    // broadcast, conflict-free), then fully-unrolled register taps ----
    float acc0[8], acc1[8];
#pragma unroll
    for (int x = 0; x < 8; ++x) { acc0[x] = 0.f; acc1[x] = 0.f; }

#pragma unroll
    for (int ic = 0; ic < 4; ++ic) {
        float r[4][12];
#pragma unroll
        for (int rr = 0; rr < 4; ++rr) {
            const float4* src = (const float4*)&xpad[(ic * 12 + h0 + rr) * 12];
            const float4 a = src[0], b = src[1], c = src[2];
            r[rr][0] = a.x; r[rr][1]  = a.y; r[rr][2]  = a.z; r[rr][3]  = a.w;
            r[rr][4] = b.x; r[rr][5]  = b.y; r[rr][6]  = b.z; r[rr][7]  = b.w;
            r[rr][8] = c.x; r[rr][9]  = c.y; r[rr][10] = c.z; r[rr][11] = c.w;
        }
#pragma unroll
        for (int kh = 0; kh < 3; ++kh) {
            const float w0 = wr[ic * 9 + kh * 3 + 0];
            const float w1 = wr[ic * 9 + kh * 3 + 1];
            const float w2 = wr[ic * 9 + kh * 3 + 2];
#pragma unroll
            for (int x = 0; x < 8; ++x) {
                acc0[x] += r[kh][x] * w0 + r[kh][x + 1] * w1 + r[kh][x + 2] * w2;
                acc1[x] += r[kh + 1][x] * w0 + r[kh + 1][x + 1] * w1 + r[kh + 1][x + 2] * w2;
            }
        }
    }
    float sum = 0.f;
#pragma unroll
    for (int x = 0; x < 8; ++x)
        sum += fmaxf(acc0[x] + bval, 0.f) + fmaxf(acc1[x] + bval, 0.f);

    partial[seg * 64 + oc] = sum;
    __syncthreads();
    if (seg == 0) {
        const float t5 = partial[oc] + partial[64 + oc] + partial[128 + oc] +
                         partial[192 + oc] + partial[256 + oc];
        emb[n * 64 + oc] = t5 * (1.f / 80.f);
    }
    __syncthreads();  // emb stores drained (vmcnt) before release

    // ---- publish + detect completion (poison-agnostic, no memset) ----
    if (tid == 0) {
        __threadfence();  // release emb row
        __hip_atomic_store(&flags[n], MAGIC, __ATOMIC_RELEASE,
                           __HIP_MEMORY_SCOPE_AGENT);
    }
    if (tid < 64) {
        const int f = __hip_atomic_load(&flags[tid], __ATOMIC_ACQUIRE,
                                        __HIP_MEMORY_SCOPE_AGENT);
        const unsigned long long m = __ballot(f == MAGIC);
        if (tid == 0) do_match = (m == 0xFFFFFFFFFFFFFFFFull);
    }
    __syncthreads();
    if (!do_match) return;
    __threadfence();  // acquire: all emb rows visible

    // =================== match phase (320 threads) ========================
    for (int i = tid; i < 2048; i += 320) {
        const int r = i >> 6, c = i & 63;
        ve[r * 65 + c] = emb[i];            // v_emb rows 0..31
        pe[r * 65 + c] = emb[2048 + i];     // p_emb rows 0..31
    }
    if (tid < 32) { claim[tid] = 64; taken[tid] = 0; }
    __syncthreads();

    // scores[p][v] = dot(p_emb[p], v_emb[v])
    for (int t = tid; t < 1024; t += 320) {
        const int p = t >> 5, v = t & 31;
        float acc = 0.f;
#pragma unroll
        for (int h = 0; h < 64; ++h)
            acc += pe[p * 65 + h] * ve[v * 65 + h];
        sc[p * 33 + v] = acc;
    }
    __syncthreads();

    // stable descending rank -> pref2[p][r] = v  (== jnp.argsort(-scores))
    for (int t = tid; t < 1024; t += 320) {
        const int p = t >> 5, v = t & 31;
        const float s = sc[p * 33 + v];
        int r = 0;
#pragma unroll
        for (int u = 0; u < 32; ++u) {
            const float su = sc[p * 33 + u];
            r += (su > s) || (su == s && u < v);
        }
        pref2[p * 33 + r] = v;
    }
    __syncthreads();
    if (tid >= 64) return;   // greedy runs in wave 0 only — no s_barrier needed

    // Greedy, round-parallel in one wave. Within a round the lowest
    // unassigned pid proposing a free position wins (atomicMin) ==
    // sequential reference semantics. Intra-wave ordering: DS ops from one
    // wave are in-order; __threadfence_block() = lgkmcnt drain + compiler
    // barrier between phases. Early exit when all pids assigned.
    int assign = -1;
#pragma unroll 1
    for (int r = 0; r < 32; ++r) {
        if (__ballot(tid < 32 && assign < 0) == 0ull) break;
        int pos = 0;
        bool want = false;
        if (tid < 32 && assign < 0) {
            pos = pref2[tid * 33 + r];
            if (taken[pos] == 0) {
                want = true;
                atomicMin(&claim[pos], tid);
            }
        }
        __threadfence_block();
        if (want && atomicAdd(&claim[pos], 0) == tid) {
            assign = pos;
            taken[pos] = 1;
            claim[pos] = 64;
        }
        __threadfence_block();
    }

    if (tid < 32) out[tid] = assign;
}

extern "C" void kernel_launch(void* const* d_in, const int* in_sizes, int n_in,
                              void* d_out, int out_size, void* d_ws, size_t ws_size,
                              hipStream_t stream) {
    const float* v_latent = (const float*)d_in[0];
    const float* p_tensor = (const float*)d_in[1];
    // d_in[2] = p_old_idx (unused by reference)
    const float* v_w = (const float*)d_in[3];
    const float* v_b = (const float*)d_in[4];
    const float* p_w = (const float*)d_in[5];
    const float* p_b = (const float*)d_in[6];

    int*   out   = (int*)d_out;
    float* emb   = (float*)d_ws;                            // 16 KB
    int*   flags = (int*)((char*)d_ws + 64 * 64 * sizeof(float));

    fused_kernel<<<64, 320, 0, stream>>>(v_latent, p_tensor, v_w, v_b, p_w, p_b,
                                         emb, flags, out);
}

// Round 4
// 83.156 us; speedup vs baseline: 1.0332x; 1.0332x over previous
//
#include <hip/hip_runtime.h>
#include <hip/hip_bf16.h>

// Single-dispatch fused kernel, FENCE-FREE cross-block handoff.
//   64 blocks x 320 threads. Block n encodes image n (n<32: video pos n,
//   else patch n-32): Conv2d(4->64,3x3,pad=1)+ReLU+avgpool -> emb row.
//
// Handoff protocol (no __threadfence / no acquire/release => no buffer_wbl2
// / buffer_inv L2-maintenance ops, which stall ~40us after the harness's
// 256MiB poison fill leaves L2 fully dirty):
//   - emb published via relaxed agent-scope atomic EXCHANGE (RMW -> executes
//     at the device coherence point, no cache maintenance)
//   - s_waitcnt vmcnt(0) (a wait, not a fence) before publishing flags[n]
//   - wave 0 RMW-reads (fetch_add 0) all 64 flags; the block whose flag
//     exchange serialized last at the coherence point sees all 64 and runs
//     match. Ties run match redundantly with identical outputs (benign).
//   - match block reads emb via relaxed RMW loads (coherence-point reads).
// Poison-agnostic: flags start 0xAAAAAAAA (or 0), never MAGIC. No memset.

#define MAGIC 0x1F2E3D4C

__device__ __forceinline__ int ws_xchg(int* p, int v) {
    return __hip_atomic_exchange(p, v, __ATOMIC_RELAXED, __HIP_MEMORY_SCOPE_AGENT);
}
__device__ __forceinline__ int ws_read(int* p) {
    return __hip_atomic_fetch_add(p, 0, __ATOMIC_RELAXED, __HIP_MEMORY_SCOPE_AGENT);
}

__global__ __launch_bounds__(320) void fused_kernel(
    const float* __restrict__ v_latent,   // [4,4,10,8,8]
    const float* __restrict__ p_tensor,   // [32,4,10,8]
    const float* __restrict__ v_w,        // [64,4,3,3]
    const float* __restrict__ v_b,        // [64]
    const float* __restrict__ p_w,        // [64,4,3,3]
    const float* __restrict__ p_b,        // [64]
    int*   emb_i,                         // ws: [64][64] f32 as int bits
    int*   flags,                         // ws: [64]
    int* __restrict__ out)                // [32] int32
{
    __shared__ float xpad[4 * 12 * 12];   // padded tile, 12-float rows (16B aligned)
    __shared__ float partial[5 * 64];
    __shared__ int   do_match;
    __shared__ float ve[32 * 65];
    __shared__ float pe[32 * 65];
    __shared__ float sc[32 * 33];
    __shared__ int   pref2[32 * 33];
    __shared__ int   claim[32];
    __shared__ int   taken[32];

    const int n   = blockIdx.x;
    const int tid = threadIdx.x;
    const bool is_video = (n < 32);
    const float* w    = is_video ? v_w : p_w;
    const float* bias = is_video ? v_b : p_b;

    // ---- stage input: zero pad ring, then interior (320 elems) ----
    for (int s = tid; s < 576; s += 320) xpad[s] = 0.f;
    __syncthreads();
    {
        const int ic  = tid / 80;
        const int rem = tid % 80;
        const int h   = rem >> 3;
        const int ww  = rem & 7;
        float val;
        if (is_video) {
            const int b = n >> 3, d = n & 7;
            val = v_latent[ic * 2560 + b * 640 + h * 64 + d * 8 + ww];
        } else {
            val = p_tensor[(n - 32) * 320 + ic * 80 + h * 8 + ww];
        }
        xpad[(ic * 12 + h + 1) * 12 + (ww + 1)] = val;
    }

    const int oc  = tid & 63;
    const int seg = tid >> 6;          // 0..4
    const int h0  = seg * 2;           // output rows h0, h0+1

    float wr[36];
    {
        const float4* w4 = (const float4*)(w + oc * 36);
#pragma unroll
        for (int i = 0; i < 9; ++i) {
            const float4 q = w4[i];
            wr[i * 4 + 0] = q.x; wr[i * 4 + 1] = q.y;
            wr[i * 4 + 2] = q.z; wr[i * 4 + 3] = q.w;
        }
    }
    const float bval = bias[oc];
    __syncthreads();

    // ---- conv: ds_read_b128 row pulls (wave-uniform broadcast), unrolled taps
    float acc0[8], acc1[8];
#pragma unroll
    for (int x = 0; x < 8; ++x) { acc0[x] = 0.f; acc1[x] = 0.f; }

#pragma unroll
    for (int ic = 0; ic < 4; ++ic) {
        float r[4][12];
#pragma unroll
        for (int rr = 0; rr < 4; ++rr) {
            const float4* src = (const float4*)&xpad[(ic * 12 + h0 + rr) * 12];
            const float4 a = src[0], b = src[1], c = src[2];
            r[rr][0] = a.x; r[rr][1]  = a.y; r[rr][2]  = a.z; r[rr][3]  = a.w;
            r[rr][4] = b.x; r[rr][5]  = b.y; r[rr][6]  = b.z; r[rr][7]  = b.w;
            r[rr][8] = c.x; r[rr][9]  = c.y; r[rr][10] = c.z; r[rr][11] = c.w;
        }
#pragma unroll
        for (int kh = 0; kh < 3; ++kh) {
            const float w0 = wr[ic * 9 + kh * 3 + 0];
            const float w1 = wr[ic * 9 + kh * 3 + 1];
            const float w2 = wr[ic * 9 + kh * 3 + 2];
#pragma unroll
            for (int x = 0; x < 8; ++x) {
                acc0[x] += r[kh][x] * w0 + r[kh][x + 1] * w1 + r[kh][x + 2] * w2;
                acc1[x] += r[kh + 1][x] * w0 + r[kh + 1][x + 1] * w1 + r[kh + 1][x + 2] * w2;
            }
        }
    }
    float sum = 0.f;
#pragma unroll
    for (int x = 0; x < 8; ++x)
        sum += fmaxf(acc0[x] + bval, 0.f) + fmaxf(acc1[x] + bval, 0.f);

    partial[seg * 64 + oc] = sum;
    __syncthreads();

    // ---- publish emb row + flag, detect completion (all in wave 0) ----
    if (tid < 64) {
        const float t5 = partial[oc] + partial[64 + oc] + partial[128 + oc] +
                         partial[192 + oc] + partial[256 + oc];
        ws_xchg(&emb_i[n * 64 + oc], __float_as_int(t5 * (1.f / 80.f)));
        __builtin_amdgcn_s_waitcnt(0);              // emb RMWs at coherence point
        asm volatile("" ::: "memory");
        if (tid == 0) ws_xchg(&flags[n], MAGIC);
        __builtin_amdgcn_s_waitcnt(0);              // flag RMW done
        asm volatile("" ::: "memory");
        const int f = ws_read(&flags[tid]);
        const unsigned long long m = __ballot(f == MAGIC);
        if (tid == 0) do_match = (m == 0xFFFFFFFFFFFFFFFFull);
    }
    __syncthreads();
    if (!do_match) return;

    // =================== match phase (320 threads) ========================
    for (int i = tid; i < 2048; i += 320) {
        const int r = i >> 6, c = i & 63;
        ve[r * 65 + c] = __int_as_float(ws_read(&emb_i[i]));          // v rows
        pe[r * 65 + c] = __int_as_float(ws_read(&emb_i[2048 + i]));   // p rows
    }
    if (tid < 32) { claim[tid] = 64; taken[tid] = 0; }
    __syncthreads();

    // scores[p][v] = dot(p_emb[p], v_emb[v])
    for (int t = tid; t < 1024; t += 320) {
        const int p = t >> 5, v = t & 31;
        float acc = 0.f;
#pragma unroll
        for (int h = 0; h < 64; ++h)
            acc += pe[p * 65 + h] * ve[v * 65 + h];
        sc[p * 33 + v] = acc;
    }
    __syncthreads();

    // stable descending rank -> pref2[p][r] = v (== jnp.argsort(-scores))
    for (int t = tid; t < 1024; t += 320) {
        const int p = t >> 5, v = t & 31;
        const float s = sc[p * 33 + v];
        int r = 0;
#pragma unroll
        for (int u = 0; u < 32; ++u) {
            const float su = sc[p * 33 + u];
            r += (su > s) || (su == s && u < v);
        }
        pref2[p * 33 + r] = v;
    }
    __syncthreads();
    if (tid >= 64) return;   // greedy in wave 0 only (lockstep, no s_barrier)

    // Greedy, round-parallel: lowest unassigned pid proposing a free position
    // wins (LDS atomicMin) == sequential reference semantics. Lockstep wave:
    // the claim[] read happens wave-wide before any winner updates stores.
    int assign = -1;
#pragma unroll 1
    for (int r = 0; r < 32; ++r) {
        if (__ballot(tid < 32 && assign < 0) == 0ull) break;
        int pos = 0;
        bool want = false;
        if (tid < 32 && assign < 0) {
            pos = pref2[tid * 33 + r];
            if (taken[pos] == 0) {
                want = true;
                atomicMin(&claim[pos], tid);
            }
        }
        __threadfence_block();                // LDS drain + compiler barrier
        if (want && claim[pos] == tid) {
            assign = pos;
            taken[pos] = 1;
            claim[pos] = 64;
        }
        __threadfence_block();
    }

    if (tid < 32) out[tid] = assign;
}

extern "C" void kernel_launch(void* const* d_in, const int* in_sizes, int n_in,
                              void* d_out, int out_size, void* d_ws, size_t ws_size,
                              hipStream_t stream) {
    const float* v_latent = (const float*)d_in[0];
    const float* p_tensor = (const float*)d_in[1];
    // d_in[2] = p_old_idx (unused by reference)
    const float* v_w = (const float*)d_in[3];
    const float* v_b = (const float*)d_in[4];
    const float* p_w = (const float*)d_in[5];
    const float* p_b = (const float*)d_in[6];

    int* out   = (int*)d_out;
    int* emb_i = (int*)d_ws;                                  // 16 KB (f32 bits)
    int* flags = (int*)((char*)d_ws + 64 * 64 * sizeof(float));

    fused_kernel<<<64, 320, 0, stream>>>(v_latent, p_tensor, v_w, v_b, p_w, p_b,
                                         emb_i, flags, out);
}